// Round 3
// baseline (161.902 us; speedup 1.0000x reference)
//
#include <hip/hip_runtime.h>
#include <hip/hip_bf16.h>

#define K_DIM 1024
#define M_DIM 4096
#define N_DIM 8192
#define BK 64
#define BM 128
#define BN 256
#define NT 16

#define OFF_A 0
#define OFF_B (BM * BK)          // 8192 elems
#define OFF_P (2 * BM * BK)      // 16384 elems
#define BUF_ELEMS (2 * BM * BK + BN * BK)   // 32768 elems = 64 KB

typedef __attribute__((ext_vector_type(8))) __bf16 bf16x8_t;
typedef __attribute__((ext_vector_type(4))) float f32x4;

#define SBAR do { __builtin_amdgcn_sched_barrier(0); \
                  __builtin_amdgcn_s_barrier(); \
                  __builtin_amdgcn_sched_barrier(0); } while (0)
#define LGKM0 do { asm volatile("s_waitcnt lgkmcnt(0)" ::: "memory"); \
                   __builtin_amdgcn_sched_barrier(0); } while (0)
#define VMCNT(n) do { asm volatile("s_waitcnt vmcnt(" #n ")" ::: "memory"); \
                      __builtin_amdgcn_sched_barrier(0); } while (0)

__device__ inline unsigned short f2bf(float f) {
    unsigned u = __float_as_uint(f);
    u += 0x7FFF + ((u >> 16) & 1);   // round-to-nearest-even
    return (unsigned short)(u >> 16);
}

__device__ __forceinline__ void gload_lds16(const void* g, void* l) {
    __builtin_amdgcn_global_load_lds(
        (const __attribute__((address_space(1))) unsigned int*)g,
        (__attribute__((address_space(3))) unsigned int*)l, 16, 0, 0);
}

// softmax over 1024 cols for wa (blocks 0..4095) and wb (blocks 4096..8191)
__global__ void dual_softmax_kernel(const float* __restrict__ wa,
                                    const float* __restrict__ wb,
                                    unsigned short* __restrict__ pa,
                                    unsigned short* __restrict__ pb) {
    const int idx = blockIdx.x;
    const float* w = (idx < M_DIM) ? wa : wb;
    unsigned short* o = (idx < M_DIM) ? pa : pb;
    const int row = idx & (M_DIM - 1);
    const int tid = threadIdx.x;
    const float4 v = reinterpret_cast<const float4*>(w + (size_t)row * K_DIM)[tid];
    float m = fmaxf(fmaxf(v.x, v.y), fmaxf(v.z, v.w));
    #pragma unroll
    for (int off = 32; off >= 1; off >>= 1) m = fmaxf(m, __shfl_xor(m, off));
    __shared__ float redm[4];
    __shared__ float reds[4];
    if ((tid & 63) == 0) redm[tid >> 6] = m;
    __syncthreads();
    m = fmaxf(fmaxf(redm[0], redm[1]), fmaxf(redm[2], redm[3]));
    const float e0 = __expf(v.x - m), e1 = __expf(v.y - m);
    const float e2 = __expf(v.z - m), e3 = __expf(v.w - m);
    float s = e0 + e1 + e2 + e3;
    #pragma unroll
    for (int off = 32; off >= 1; off >>= 1) s += __shfl_xor(s, off);
    if ((tid & 63) == 0) reds[tid >> 6] = s;
    __syncthreads();
    s = reds[0] + reds[1] + reds[2] + reds[3];
    const float inv = 1.0f / s;
    ushort4 r;
    r.x = f2bf(e0 * inv); r.y = f2bf(e1 * inv);
    r.z = f2bf(e2 * inv); r.w = f2bf(e3 * inv);
    reinterpret_cast<ushort4*>(o + (size_t)row * K_DIM)[tid] = r;
}

// prev (K x N, f32) -> prevT (N x K, bf16)
__global__ void transpose_conv_kernel(const float* __restrict__ src,
                                      unsigned short* __restrict__ dst) {
    __shared__ float t[32][33];
    const int n0 = blockIdx.x * 32;
    const int k0 = blockIdx.y * 32;
    const int tx = threadIdx.x, ty = threadIdx.y;   // 32 x 8
    #pragma unroll
    for (int i = ty; i < 32; i += 8)
        t[i][tx] = src[(size_t)(k0 + i) * N_DIM + n0 + tx];
    __syncthreads();
    #pragma unroll
    for (int i = ty; i < 32; i += 8)
        dst[(size_t)(n0 + i) * K_DIM + k0 + tx] = f2bf(t[tx][i]);
}

__global__ void coef_kernel(const float* __restrict__ tw,
                            float4* __restrict__ coef) {
    const int r = blockIdx.x * 256 + threadIdx.x;
    float p[16];
    float m = -1e30f;
    #pragma unroll
    for (int k = 0; k < 16; ++k) { p[k] = tw[k * M_DIM + r]; m = fmaxf(m, p[k]); }
    float s = 0.f;
    #pragma unroll
    for (int k = 0; k < 16; ++k) { p[k] = __expf(p[k] - m); s += p[k]; }
    const float inv = 1.f / s;
    #pragma unroll
    for (int k = 0; k < 16; ++k) p[k] *= inv;
    const float cA  = p[2]+p[3]+p[6]+p[7]-p[8]-p[9]-p[12]-p[13];
    const float cB  = p[4]+p[5]+p[6]+p[7]-p[8]-p[9]-p[10]-p[11];
    const float cAB = p[1]-p[2]-p[4]-2.f*p[6]-p[7]+p[8]+2.f*p[9]+p[11]+p[13]-p[14];
    const float c0  = p[8]+p[9]+p[10]+p[11]+p[12]+p[13]+p[14]+p[15];
    coef[r] = make_float4(cA, cB, cAB, c0);
}

__device__ __forceinline__ void load_frags4(const unsigned short* lbase, int row0,
                                            int fk16, bf16x8_t (&f)[4]) {
    #pragma unroll
    for (int i = 0; i < 4; ++i) {
        const int row = row0 + i * 16;
        f[i] = *reinterpret_cast<const bf16x8_t*>(
            (const char*)lbase + row * 128 + ((fk16 ^ (row & 7)) * 16));
    }
}

__device__ __forceinline__ void mfma_block(const bf16x8_t (&a)[4], const bf16x8_t (&p)[4],
                                           f32x4 (&acc)[4][4]) {
    #pragma unroll
    for (int mi = 0; mi < 4; ++mi)
        #pragma unroll
        for (int ni = 0; ni < 4; ++ni)
            acc[mi][ni] = __builtin_amdgcn_mfma_f32_16x16x32_bf16(
                a[mi], p[ni], acc[mi][ni], 0, 0, 0);
}

// Fused dual GEMM, 8-wave 128x256 tile, BK=64, double-buffered LDS,
// 4-phase counted-vmcnt schedule (T3+T4+T5). Chunk issue order per tile:
// A(2/wave) @P1, P(2) @P2, P(2) @P3, B(2) @P4 -> FIFO lets vmcnt(2) at
// P4-end cover A+P (needed next P1) and vmcnt(2) at P1-end cover B
// (needed at P2), with 2 loads always in flight.
__global__ __launch_bounds__(512, 2)
void dual_gemm_kernel(const unsigned short* __restrict__ pa,
                      const unsigned short* __restrict__ pb,
                      const unsigned short* __restrict__ pv,
                      const float4* __restrict__ coef,
                      float* __restrict__ out) {
    __shared__ unsigned short lds[2 * BUF_ELEMS];   // 128 KB

    const int tid = threadIdx.x;
    const int lane = tid & 63;
    const int w = tid >> 6;            // 0..7
    const int wm = w >> 2, wn = w & 3; // 2 (M) x 4 (N)

    // XCD-aware swizzle: 1024 wgs, 8 XCDs, 128 each (bijective).
    const int wg = blockIdx.x;
    const int swz = (wg & 7) * 128 + (wg >> 3);
    const int bm = swz >> 5;   // 0..31
    const int bn = swz & 31;   // 0..31

    const int sub_row = lane >> 3;                // 0..7
    const int scol16  = (lane & 7) ^ sub_row;     // pre-swizzled src 16B col

    const unsigned short* gA = pa + (size_t)(bm * BM) * K_DIM;
    const unsigned short* gB = pb + (size_t)(bm * BM) * K_DIM;
    const unsigned short* gP = pv + (size_t)(bn * BN) * K_DIM;

    const int fr  = lane & 15;
    const int fkb = lane >> 4;         // 0..3 (16B col in K-row)
    const int arow0 = wm * 64 + fr;
    const int prow0 = wn * 64 + fr;

    f32x4 accA[4][4], accB[4][4];
    const f32x4 z = {0.f, 0.f, 0.f, 0.f};
    #pragma unroll
    for (int i = 0; i < 4; ++i)
        #pragma unroll
        for (int j = 0; j < 4; ++j) { accA[i][j] = z; accB[i][j] = z; }

    auto stage = [&](const unsigned short* gbase, int lds_elem_off, int chunk, int k) {
        const int r = chunk * 8 + sub_row;
        const char* src = (const char*)(gbase + (size_t)r * K_DIM + k) + scol16 * 16;
        char* dst = (char*)&lds[lds_elem_off] + chunk * 1024;
        gload_lds16(src, dst);
    };

    // prologue: stage tile 0, order A, P, B
    stage(gA, OFF_A, 2 * w, 0);     stage(gA, OFF_A, 2 * w + 1, 0);
    stage(gP, OFF_P, 4 * w, 0);     stage(gP, OFF_P, 4 * w + 1, 0);
    stage(gP, OFF_P, 4 * w + 2, 0); stage(gP, OFF_P, 4 * w + 3, 0);
    stage(gB, OFF_B, 2 * w, 0);     stage(gB, OFF_B, 2 * w + 1, 0);
    VMCNT(2);          // A+P of tile 0 landed; B (2) in flight
    SBAR;

    for (int t = 0; t < NT - 1; ++t) {
        const int kn = (t + 1) * BK;
        const int co = (t & 1) * BUF_ELEMS;
        const int no = co ^ BUF_ELEMS;
        bf16x8_t af[4], pf[4], bfv[4];

        // ---- P1: accA kk0 ----
        load_frags4(&lds[co + OFF_A], arow0, fkb, af);
        load_frags4(&lds[co + OFF_P], prow0, fkb, pf);
        stage(gA, no + OFF_A, 2 * w, kn); stage(gA, no + OFF_A, 2 * w + 1, kn);
        VMCNT(2);      // drains this tile's B (oldest); next-A in flight
        SBAR;
        LGKM0;
        __builtin_amdgcn_s_setprio(1);
        mfma_block(af, pf, accA);
        __builtin_amdgcn_s_setprio(0);
        SBAR;

        // ---- P2: accB kk0 (reuses pf) ----
        load_frags4(&lds[co + OFF_B], arow0, fkb, bfv);
        stage(gP, no + OFF_P, 4 * w, kn); stage(gP, no + OFF_P, 4 * w + 1, kn);
        SBAR;
        LGKM0;
        __builtin_amdgcn_s_setprio(1);
        mfma_block(bfv, pf, accB);
        __builtin_amdgcn_s_setprio(0);
        SBAR;

        // ---- P3: accA kk1 ----
        load_frags4(&lds[co + OFF_A], arow0, fkb + 4, af);
        load_frags4(&lds[co + OFF_P], prow0, fkb + 4, pf);
        stage(gP, no + OFF_P, 4 * w + 2, kn); stage(gP, no + OFF_P, 4 * w + 3, kn);
        SBAR;
        LGKM0;
        __builtin_amdgcn_s_setprio(1);
        mfma_block(af, pf, accA);
        __builtin_amdgcn_s_setprio(0);
        SBAR;

        // ---- P4: accB kk1 ----
        load_frags4(&lds[co + OFF_B], arow0, fkb + 4, bfv);
        stage(gB, no + OFF_B, 2 * w, kn); stage(gB, no + OFF_B, 2 * w + 1, kn);
        VMCNT(2);      // drains next tile's A+P (6 oldest); its B in flight
        SBAR;
        LGKM0;
        __builtin_amdgcn_s_setprio(1);
        mfma_block(bfv, pf, accB);
        __builtin_amdgcn_s_setprio(0);
        SBAR;
    }

    // ---- tail tile (t = 15, buffer 1): no staging, drain B then compute ----
    {
        const int co = ((NT - 1) & 1) * BUF_ELEMS;
        bf16x8_t af[4], pf[4], bfv[4];
        load_frags4(&lds[co + OFF_A], arow0, fkb, af);
        load_frags4(&lds[co + OFF_P], prow0, fkb, pf);
        VMCNT(0);
        SBAR;
        LGKM0;
        __builtin_amdgcn_s_setprio(1);
        mfma_block(af, pf, accA);
        __builtin_amdgcn_s_setprio(0);
        load_frags4(&lds[co + OFF_B], arow0, fkb, bfv);
        mfma_block(bfv, pf, accB);
        load_frags4(&lds[co + OFF_A], arow0, fkb + 4, af);
        load_frags4(&lds[co + OFF_P], prow0, fkb + 4, pf);
        mfma_block(af, pf, accA);
        load_frags4(&lds[co + OFF_B], arow0, fkb + 4, bfv);
        mfma_block(bfv, pf, accB);
    }

    // epilogue: D layout col=lane&15, row=(lane>>4)*4+reg
    const int row_grp = lane >> 4;
    #pragma unroll
    for (int mi = 0; mi < 4; ++mi) {
        #pragma unroll
        for (int ni = 0; ni < 4; ++ni) {
            const int gr0 = bm * BM + wm * 64 + mi * 16 + row_grp * 4;
            const int gc  = bn * BN + wn * 64 + ni * 16 + (lane & 15);
            #pragma unroll
            for (int i = 0; i < 4; ++i) {
                const int r = gr0 + i;
                const float4 cf = coef[r];
                const float av = accA[mi][ni][i];
                const float bv = accB[mi][ni][i];
                out[(size_t)r * N_DIM + gc] =
                    fmaf(cf.z, av * bv, fmaf(cf.x, av, fmaf(cf.y, bv, cf.w)));
            }
        }
    }
}

extern "C" void kernel_launch(void* const* d_in, const int* in_sizes, int n_in,
                              void* d_out, int out_size, void* d_ws, size_t ws_size,
                              hipStream_t stream) {
    const float* prev = (const float*)d_in[0];   // (1024, 8192)
    const float* wa   = (const float*)d_in[1];   // (4096, 1024)
    const float* wb   = (const float*)d_in[2];   // (4096, 1024)
    const float* tw   = (const float*)d_in[3];   // (16, 4096)
    float* out = (float*)d_out;                  // (4096, 8192)

    char* ws = (char*)d_ws;
    unsigned short* pa = (unsigned short*)ws;                        // 8 MB
    unsigned short* pb = (unsigned short*)(ws + 8388608);            // 8 MB
    unsigned short* pv = (unsigned short*)(ws + 16777216);           // 16 MB
    float4* coef       = (float4*)(ws + 33554432);                   // 64 KB

    dual_softmax_kernel<<<2 * M_DIM, 256, 0, stream>>>(wa, wb, pa, pb);
    transpose_conv_kernel<<<dim3(N_DIM / 32, K_DIM / 32), dim3(32, 8), 0, stream>>>(prev, pv);
    coef_kernel<<<M_DIM / 256, 256, 0, stream>>>(tw, coef);
    dual_gemm_kernel<<<dim3((M_DIM / BM) * (N_DIM / BN)), 512, 0, stream>>>(pa, pb, pv, coef, out);
}

// Round 4
// 155.048 us; speedup vs baseline: 1.0442x; 1.0442x over previous
//
#include <hip/hip_runtime.h>
#include <hip/hip_bf16.h>

#define K_DIM 1024
#define M_DIM 4096
#define N_DIM 8192
#define BK 64
#define BM 128
#define BN 256
#define NT 16

#define OFF_A 0
#define OFF_B (BM * BK)          // 8192 elems
#define OFF_P (2 * BM * BK)      // 16384 elems
#define BUF_ELEMS (2 * BM * BK + BN * BK)   // 32768 elems = 64 KB

typedef __attribute__((ext_vector_type(8))) __bf16 bf16x8_t;
typedef __attribute__((ext_vector_type(4))) float f32x4;

#define SBAR do { __builtin_amdgcn_sched_barrier(0); \
                  __builtin_amdgcn_s_barrier(); \
                  __builtin_amdgcn_sched_barrier(0); } while (0)
#define LGKM0 do { asm volatile("s_waitcnt lgkmcnt(0)" ::: "memory"); \
                   __builtin_amdgcn_sched_barrier(0); } while (0)
#define VMCNT(n) do { asm volatile("s_waitcnt vmcnt(" #n ")" ::: "memory"); \
                      __builtin_amdgcn_sched_barrier(0); } while (0)

__device__ inline unsigned short f2bf(float f) {
    unsigned u = __float_as_uint(f);
    u += 0x7FFF + ((u >> 16) & 1);   // round-to-nearest-even
    return (unsigned short)(u >> 16);
}

__device__ __forceinline__ void gload_lds16(const void* g, void* l) {
    __builtin_amdgcn_global_load_lds(
        (const __attribute__((address_space(1))) unsigned int*)g,
        (__attribute__((address_space(3))) unsigned int*)l, 16, 0, 0);
}

// softmax over 1024 cols for wa (blocks 0..4095) and wb (blocks 4096..8191)
__global__ void dual_softmax_kernel(const float* __restrict__ wa,
                                    const float* __restrict__ wb,
                                    unsigned short* __restrict__ pa,
                                    unsigned short* __restrict__ pb) {
    const int idx = blockIdx.x;
    const float* w = (idx < M_DIM) ? wa : wb;
    unsigned short* o = (idx < M_DIM) ? pa : pb;
    const int row = idx & (M_DIM - 1);
    const int tid = threadIdx.x;
    const float4 v = reinterpret_cast<const float4*>(w + (size_t)row * K_DIM)[tid];
    float m = fmaxf(fmaxf(v.x, v.y), fmaxf(v.z, v.w));
    #pragma unroll
    for (int off = 32; off >= 1; off >>= 1) m = fmaxf(m, __shfl_xor(m, off));
    __shared__ float redm[4];
    __shared__ float reds[4];
    if ((tid & 63) == 0) redm[tid >> 6] = m;
    __syncthreads();
    m = fmaxf(fmaxf(redm[0], redm[1]), fmaxf(redm[2], redm[3]));
    const float e0 = __expf(v.x - m), e1 = __expf(v.y - m);
    const float e2 = __expf(v.z - m), e3 = __expf(v.w - m);
    float s = e0 + e1 + e2 + e3;
    #pragma unroll
    for (int off = 32; off >= 1; off >>= 1) s += __shfl_xor(s, off);
    if ((tid & 63) == 0) reds[tid >> 6] = s;
    __syncthreads();
    s = reds[0] + reds[1] + reds[2] + reds[3];
    const float inv = 1.0f / s;
    ushort4 r;
    r.x = f2bf(e0 * inv); r.y = f2bf(e1 * inv);
    r.z = f2bf(e2 * inv); r.w = f2bf(e3 * inv);
    reinterpret_cast<ushort4*>(o + (size_t)row * K_DIM)[tid] = r;
}

// prev (K x N, f32) -> prevT (N x K, bf16)
__global__ void transpose_conv_kernel(const float* __restrict__ src,
                                      unsigned short* __restrict__ dst) {
    __shared__ float t[32][33];
    const int n0 = blockIdx.x * 32;
    const int k0 = blockIdx.y * 32;
    const int tx = threadIdx.x, ty = threadIdx.y;   // 32 x 8
    #pragma unroll
    for (int i = ty; i < 32; i += 8)
        t[i][tx] = src[(size_t)(k0 + i) * N_DIM + n0 + tx];
    __syncthreads();
    #pragma unroll
    for (int i = ty; i < 32; i += 8)
        dst[(size_t)(n0 + i) * K_DIM + k0 + tx] = f2bf(t[tx][i]);
}

__global__ void coef_kernel(const float* __restrict__ tw,
                            float4* __restrict__ coef) {
    const int r = blockIdx.x * 256 + threadIdx.x;
    float p[16];
    float m = -1e30f;
    #pragma unroll
    for (int k = 0; k < 16; ++k) { p[k] = tw[k * M_DIM + r]; m = fmaxf(m, p[k]); }
    float s = 0.f;
    #pragma unroll
    for (int k = 0; k < 16; ++k) { p[k] = __expf(p[k] - m); s += p[k]; }
    const float inv = 1.f / s;
    #pragma unroll
    for (int k = 0; k < 16; ++k) p[k] *= inv;
    const float cA  = p[2]+p[3]+p[6]+p[7]-p[8]-p[9]-p[12]-p[13];
    const float cB  = p[4]+p[5]+p[6]+p[7]-p[8]-p[9]-p[10]-p[11];
    const float cAB = p[1]-p[2]-p[4]-2.f*p[6]-p[7]+p[8]+2.f*p[9]+p[11]+p[13]-p[14];
    const float c0  = p[8]+p[9]+p[10]+p[11]+p[12]+p[13]+p[14]+p[15];
    coef[r] = make_float4(cA, cB, cAB, c0);
}

__device__ __forceinline__ void load_frags4(const unsigned short* lbase, int row0,
                                            int fk16, bf16x8_t (&f)[4]) {
    #pragma unroll
    for (int i = 0; i < 4; ++i) {
        const int row = row0 + i * 16;
        f[i] = *reinterpret_cast<const bf16x8_t*>(
            (const char*)lbase + row * 128 + ((fk16 ^ (row & 7)) * 16));
    }
}

__device__ __forceinline__ void mfma_block(const bf16x8_t (&a)[4], const bf16x8_t (&p)[4],
                                           f32x4 (&acc)[4][4]) {
    #pragma unroll
    for (int mi = 0; mi < 4; ++mi)
        #pragma unroll
        for (int ni = 0; ni < 4; ++ni)
            acc[mi][ni] = __builtin_amdgcn_mfma_f32_16x16x32_bf16(
                a[mi], p[ni], acc[mi][ni], 0, 0, 0);
}

// Fused dual GEMM, 8-wave 128x256 tile, BK=64, double-buffered LDS,
// 4-phase counted-vmcnt schedule. Issue plan per tile t (loads for t+1):
//   P1: issue A'(2)+P'(4); VMCNT(6) drains cur-B (cover ~2.5 phases)
//   P2: issue B'(2); no drain
//   P4: VMCNT(2) drains A'+P' (cover ~3 phases), leaves B' in flight
// Every drain waits only on loads with >=2.5 phases of MFMA/ds_read cover.
__global__ __launch_bounds__(512, 2)
void dual_gemm_kernel(const unsigned short* __restrict__ pa,
                      const unsigned short* __restrict__ pb,
                      const unsigned short* __restrict__ pv,
                      const float4* __restrict__ coef,
                      float* __restrict__ out) {
    __shared__ unsigned short lds[2 * BUF_ELEMS];   // 128 KB

    const int tid = threadIdx.x;
    const int lane = tid & 63;
    const int w = tid >> 6;            // 0..7
    const int wm = w >> 2, wn = w & 3; // 2 (M) x 4 (N)

    const int bm = blockIdx.y;
    const int bn = blockIdx.x;

    const int sub_row = lane >> 3;                // 0..7
    const int scol16  = (lane & 7) ^ sub_row;     // pre-swizzled src 16B col

    const unsigned short* gA = pa + (size_t)(bm * BM) * K_DIM;
    const unsigned short* gB = pb + (size_t)(bm * BM) * K_DIM;
    const unsigned short* gP = pv + (size_t)(bn * BN) * K_DIM;

    const int fr  = lane & 15;
    const int fkb = lane >> 4;         // 0..3 (16B col in K-row)
    const int arow0 = wm * 64 + fr;
    const int prow0 = wn * 64 + fr;

    f32x4 accA[4][4], accB[4][4];
    const f32x4 z = {0.f, 0.f, 0.f, 0.f};
    #pragma unroll
    for (int i = 0; i < 4; ++i)
        #pragma unroll
        for (int j = 0; j < 4; ++j) { accA[i][j] = z; accB[i][j] = z; }

    auto stage = [&](const unsigned short* gbase, int lds_elem_off, int chunk, int k) {
        const int r = chunk * 8 + sub_row;
        const char* src = (const char*)(gbase + (size_t)r * K_DIM + k) + scol16 * 16;
        char* dst = (char*)&lds[lds_elem_off] + chunk * 1024;
        gload_lds16(src, dst);
    };

    // prologue: tile 0, issue order must match steady state: A, P, then B
    stage(gA, OFF_A, 2 * w, 0);     stage(gA, OFF_A, 2 * w + 1, 0);
    stage(gP, OFF_P, 4 * w, 0);     stage(gP, OFF_P, 4 * w + 1, 0);
    stage(gP, OFF_P, 4 * w + 2, 0); stage(gP, OFF_P, 4 * w + 3, 0);
    stage(gB, OFF_B, 2 * w, 0);     stage(gB, OFF_B, 2 * w + 1, 0);
    VMCNT(2);          // A+P of tile 0 landed; B(2) in flight
    SBAR;

    for (int t = 0; t < NT - 1; ++t) {
        const int kn = (t + 1) * BK;
        const int co = (t & 1) * BUF_ELEMS;
        const int no = co ^ BUF_ELEMS;
        bf16x8_t af[4], pf[4], bfv[4];

        // ---- P1: accA kk0; issue next A + next P ----
        load_frags4(&lds[co + OFF_A], arow0, fkb, af);
        load_frags4(&lds[co + OFF_P], prow0, fkb, pf);
        stage(gA, no + OFF_A, 2 * w, kn); stage(gA, no + OFF_A, 2 * w + 1, kn);
        stage(gP, no + OFF_P, 4 * w, kn); stage(gP, no + OFF_P, 4 * w + 1, kn);
        stage(gP, no + OFF_P, 4 * w + 2, kn); stage(gP, no + OFF_P, 4 * w + 3, kn);
        VMCNT(6);      // drains cur-B (issued prev-P2, ~2.5 phases ago)
        SBAR;
        LGKM0;
        __builtin_amdgcn_s_setprio(1);
        mfma_block(af, pf, accA);
        __builtin_amdgcn_s_setprio(0);
        SBAR;

        // ---- P2: accB kk0 (reuses pf); issue next B ----
        load_frags4(&lds[co + OFF_B], arow0, fkb, bfv);
        stage(gB, no + OFF_B, 2 * w, kn); stage(gB, no + OFF_B, 2 * w + 1, kn);
        SBAR;
        LGKM0;
        __builtin_amdgcn_s_setprio(1);
        mfma_block(bfv, pf, accB);
        __builtin_amdgcn_s_setprio(0);
        SBAR;

        // ---- P3: accA kk1 ----
        load_frags4(&lds[co + OFF_A], arow0, fkb + 4, af);
        load_frags4(&lds[co + OFF_P], prow0, fkb + 4, pf);
        SBAR;
        LGKM0;
        __builtin_amdgcn_s_setprio(1);
        mfma_block(af, pf, accA);
        __builtin_amdgcn_s_setprio(0);
        SBAR;

        // ---- P4: accB kk1; drain next A+P before buffer swap ----
        load_frags4(&lds[co + OFF_B], arow0, fkb + 4, bfv);
        VMCNT(2);      // drains next A+P (issued this P1, ~3 phases ago)
        SBAR;
        LGKM0;
        __builtin_amdgcn_s_setprio(1);
        mfma_block(bfv, pf, accB);
        __builtin_amdgcn_s_setprio(0);
        SBAR;
    }

    // ---- tail tile (t = 15, buffer 1): drain in-flight B, then compute ----
    {
        const int co = ((NT - 1) & 1) * BUF_ELEMS;
        bf16x8_t af[4], pf[4], bfv[4];
        load_frags4(&lds[co + OFF_A], arow0, fkb, af);
        load_frags4(&lds[co + OFF_P], prow0, fkb, pf);
        VMCNT(0);      // tail-B landed long ago; ~free
        SBAR;
        LGKM0;
        __builtin_amdgcn_s_setprio(1);
        mfma_block(af, pf, accA);
        __builtin_amdgcn_s_setprio(0);
        load_frags4(&lds[co + OFF_B], arow0, fkb, bfv);
        mfma_block(bfv, pf, accB);
        load_frags4(&lds[co + OFF_A], arow0, fkb + 4, af);
        load_frags4(&lds[co + OFF_P], prow0, fkb + 4, pf);
        mfma_block(af, pf, accA);
        load_frags4(&lds[co + OFF_B], arow0, fkb + 4, bfv);
        mfma_block(bfv, pf, accB);
    }

    // epilogue: D layout col=lane&15, row=(lane>>4)*4+reg
    const int row_grp = lane >> 4;
    #pragma unroll
    for (int mi = 0; mi < 4; ++mi) {
        #pragma unroll
        for (int ni = 0; ni < 4; ++ni) {
            const int gr0 = bm * BM + wm * 64 + mi * 16 + row_grp * 4;
            const int gc  = bn * BN + wn * 64 + ni * 16 + (lane & 15);
            #pragma unroll
            for (int i = 0; i < 4; ++i) {
                const int r = gr0 + i;
                const float4 cf = coef[r];
                const float av = accA[mi][ni][i];
                const float bv = accB[mi][ni][i];
                out[(size_t)r * N_DIM + gc] =
                    fmaf(cf.z, av * bv, fmaf(cf.x, av, fmaf(cf.y, bv, cf.w)));
            }
        }
    }
}

extern "C" void kernel_launch(void* const* d_in, const int* in_sizes, int n_in,
                              void* d_out, int out_size, void* d_ws, size_t ws_size,
                              hipStream_t stream) {
    const float* prev = (const float*)d_in[0];   // (1024, 8192)
    const float* wa   = (const float*)d_in[1];   // (4096, 1024)
    const float* wb   = (const float*)d_in[2];   // (4096, 1024)
    const float* tw   = (const float*)d_in[3];   // (16, 4096)
    float* out = (float*)d_out;                  // (4096, 8192)

    char* ws = (char*)d_ws;
    unsigned short* pa = (unsigned short*)ws;                        // 8 MB
    unsigned short* pb = (unsigned short*)(ws + 8388608);            // 8 MB
    unsigned short* pv = (unsigned short*)(ws + 16777216);           // 16 MB
    float4* coef       = (float4*)(ws + 33554432);                   // 64 KB

    dual_softmax_kernel<<<2 * M_DIM, 256, 0, stream>>>(wa, wb, pa, pb);
    transpose_conv_kernel<<<dim3(N_DIM / 32, K_DIM / 32), dim3(32, 8), 0, stream>>>(prev, pv);
    coef_kernel<<<M_DIM / 256, 256, 0, stream>>>(tw, coef);
    dual_gemm_kernel<<<dim3(N_DIM / BN, M_DIM / BM), 512, 0, stream>>>(pa, pb, pv, coef, out);
}